// Round 3
// baseline (464.577 us; speedup 1.0000x reference)
//
#include <hip/hip_runtime.h>
#include <math.h>

// Problem constants (B,T,J,D) = (64, 2048, 128, 512)
#define BB 64
#define TT 2048
#define JJ 128
#define DD 512

typedef short short8 __attribute__((ext_vector_type(8)));
typedef float f32x4 __attribute__((ext_vector_type(4)));

__device__ inline unsigned pk_hi(float a, float b) {
  // (hi16(a)) | (hi16(b) << 16) -- bf16 truncation pack of 2 fp32
  return __builtin_amdgcn_perm(__float_as_uint(b), __float_as_uint(a), 0x07060302u);
}
__device__ inline float truncbf(float x) {
  return __uint_as_float(__float_as_uint(x) & 0xFFFF0000u);
}
// 8 fp32 (two float4) -> hi chunk (8 bf16) + lo chunk (8 bf16)
__device__ inline void pack8(float4 a, float4 b, uint4& h, uint4& l) {
  h = make_uint4(pk_hi(a.x, a.y), pk_hi(a.z, a.w), pk_hi(b.x, b.y), pk_hi(b.z, b.w));
  float l0 = a.x - truncbf(a.x), l1 = a.y - truncbf(a.y);
  float l2 = a.z - truncbf(a.z), l3 = a.w - truncbf(a.w);
  float l4 = b.x - truncbf(b.x), l5 = b.y - truncbf(b.y);
  float l6 = b.z - truncbf(b.z), l7 = b.w - truncbf(b.w);
  l = make_uint4(pk_hi(l0, l1), pk_hi(l2, l3), pk_hi(l4, l5), pk_hi(l6, l7));
}
__device__ inline short8 bc8(uint4 u) { return __builtin_bit_cast(short8, u); }

// ---------------- Kernel A: S[b][j][t] = sum_d Q[b][j][d]*w[d]*C[b][t][d] ----
// 128x128 tile, split-bf16 (hi/lo) 3-MFMA scheme, 16 K-steps of 32.
// A (Q) fragments loaded DIRECTLY from global (L2/L3-hot, both MFMA operands
// are [row][8 consecutive k]); B (C-matrix) staged through LDS with explicit
// next-iteration register prefetch. LDS = 16 KB.
__global__ __launch_bounds__(256, 3)
void sim_gemm_mfma(const float* __restrict__ Qm, const float* __restrict__ Cm,
                   const float* __restrict__ w, float* __restrict__ S) {
  __shared__ uint4 Bhi[128 * 4];
  __shared__ uint4 Blo[128 * 4];

  const int tid = threadIdx.x;
  const int b = blockIdx.y;
  const int t0 = blockIdx.x * 128;

  // ---- staging: row sr (0..127), k-half h (fp32 k = h*16 .. h*16+15)
  const int sr = tid >> 1;
  const int h = tid & 1;
  const int ssw = (sr >> 1) & 3;
  const int slot0 = sr * 4 + ((2 * h + 0) ^ ssw);
  const int slot1 = sr * 4 + ((2 * h + 1) ^ ssw);
  const float* cp = Cm + ((size_t)b * TT + t0 + sr) * DD + h * 16;

  // ---- MFMA fragment assignment: 4 waves in 2x2 over 128x128
  const int lane = tid & 63;
  const int wv = tid >> 6;
  const int wm = (wv & 1) * 64;
  const int wn = (wv >> 1) * 64;
  const int l15 = lane & 15;
  const int q = lane >> 4;
  const int fchunk = q ^ ((l15 >> 1) & 3);

  int bslot[4];
#pragma unroll
  for (int i = 0; i < 4; i++) bslot[i] = (wn + i * 16 + l15) * 4 + fchunk;

  // A-operand: lane reads Q[wm + mi*16 + l15][k0 + q*8 .. +7] directly
  const float* qrow = Qm + ((size_t)b * JJ + wm + l15) * DD + q * 8;
  const float* wp = w + q * 8;

  f32x4 acc[4][4] = {};

  // prefetch iter 0's C chunk
  float4 c0 = *(const float4*)(cp + 0);
  float4 c1 = *(const float4*)(cp + 4);
  float4 c2 = *(const float4*)(cp + 8);
  float4 c3 = *(const float4*)(cp + 12);

  for (int ks = 0; ks < 16; ks++) {
    const int k0 = ks * 32;
    __syncthreads();  // previous iter's fragment reads complete
    {
      uint4 hh, ll;
      pack8(c0, c1, hh, ll);
      Bhi[slot0] = hh; Blo[slot0] = ll;
      pack8(c2, c3, hh, ll);
      Bhi[slot1] = hh; Blo[slot1] = ll;
    }
    // issue next iter's C loads now (one full iteration of lead time)
    const int kn = (ks < 15) ? k0 + 32 : 0;
    c0 = *(const float4*)(cp + kn + 0);
    c1 = *(const float4*)(cp + kn + 4);
    c2 = *(const float4*)(cp + kn + 8);
    c3 = *(const float4*)(cp + kn + 12);
    __syncthreads();  // B tile visible

    // w for this iter's k-octet (uniform across l15 -> cache broadcast)
    const float4 w0 = *(const float4*)(wp + k0);
    const float4 w1 = *(const float4*)(wp + k0 + 4);

    short8 bh[4], bl[4];
#pragma unroll
    for (int ni = 0; ni < 4; ni++) {
      bh[ni] = bc8(Bhi[bslot[ni]]);
      bl[ni] = bc8(Blo[bslot[ni]]);
    }

#pragma unroll
    for (int mi = 0; mi < 4; mi++) {
      const float* qp = qrow + (size_t)(mi * 16) * DD + k0;
      float4 va = *(const float4*)(qp);
      float4 vb = *(const float4*)(qp + 4);
      va.x *= w0.x; va.y *= w0.y; va.z *= w0.z; va.w *= w0.w;
      vb.x *= w1.x; vb.y *= w1.y; vb.z *= w1.z; vb.w *= w1.w;
      uint4 ah4, al4;
      pack8(va, vb, ah4, al4);
      short8 ah = bc8(ah4), al = bc8(al4);
#pragma unroll
      for (int ni = 0; ni < 4; ni++) {
        acc[mi][ni] = __builtin_amdgcn_mfma_f32_16x16x32_bf16(ah, bh[ni], acc[mi][ni], 0, 0, 0);
        acc[mi][ni] = __builtin_amdgcn_mfma_f32_16x16x32_bf16(al, bh[ni], acc[mi][ni], 0, 0, 0);
        acc[mi][ni] = __builtin_amdgcn_mfma_f32_16x16x32_bf16(ah, bl[ni], acc[mi][ni], 0, 0, 0);
      }
    }
  }

  // epilogue: C/D layout col=lane&15, row=(lane>>4)*4+reg
#pragma unroll
  for (int mi = 0; mi < 4; mi++) {
#pragma unroll
    for (int ni = 0; ni < 4; ni++) {
      const int j = wm + mi * 16 + q * 4;
      const int t = t0 + wn + ni * 16 + l15;
      float* dst = S + ((size_t)b * JJ + j) * TT + t;
      dst[0 * TT] = acc[mi][ni][0];
      dst[1 * TT] = acc[mi][ni][1];
      dst[2 * TT] = acc[mi][ni][2];
      dst[3 * TT] = acc[mi][ni][3];
    }
  }
}

// ---------------- Kernel B: per-(b,j) softmax stats over valid t -------------
__global__ __launch_bounds__(256)
void softmax_stats_kernel(const float* __restrict__ S, const int* __restrict__ qlen,
                          const int* __restrict__ clen, float* __restrict__ m_out,
                          float* __restrict__ r_out) {
  const int j = blockIdx.x;
  const int b = blockIdx.y;
  if (j >= qlen[b]) return;
  const int cl = clen[b];
  const int tid = threadIdx.x;
  const float4* row = (const float4*)(S + ((size_t)b * JJ + j) * TT);

  float4 v0 = row[tid];
  float4 v1 = row[tid + 256];
  const int t0 = tid * 4;
  const int t1 = (tid + 256) * 4;
  const float NEG = -3.4e38f;

  float m = NEG;
  m = fmaxf(m, (t0 + 0 < cl) ? v0.x : NEG);
  m = fmaxf(m, (t0 + 1 < cl) ? v0.y : NEG);
  m = fmaxf(m, (t0 + 2 < cl) ? v0.z : NEG);
  m = fmaxf(m, (t0 + 3 < cl) ? v0.w : NEG);
  m = fmaxf(m, (t1 + 0 < cl) ? v1.x : NEG);
  m = fmaxf(m, (t1 + 1 < cl) ? v1.y : NEG);
  m = fmaxf(m, (t1 + 2 < cl) ? v1.z : NEG);
  m = fmaxf(m, (t1 + 3 < cl) ? v1.w : NEG);

  __shared__ float red[8];
#pragma unroll
  for (int off = 32; off > 0; off >>= 1) m = fmaxf(m, __shfl_down(m, off));
  if ((tid & 63) == 0) red[tid >> 6] = m;
  __syncthreads();
  m = fmaxf(fmaxf(red[0], red[1]), fmaxf(red[2], red[3]));

  float s = 0.f;
  s += (t0 + 0 < cl) ? __expf(v0.x - m) : 0.f;
  s += (t0 + 1 < cl) ? __expf(v0.y - m) : 0.f;
  s += (t0 + 2 < cl) ? __expf(v0.z - m) : 0.f;
  s += (t0 + 3 < cl) ? __expf(v0.w - m) : 0.f;
  s += (t1 + 0 < cl) ? __expf(v1.x - m) : 0.f;
  s += (t1 + 1 < cl) ? __expf(v1.y - m) : 0.f;
  s += (t1 + 2 < cl) ? __expf(v1.z - m) : 0.f;
  s += (t1 + 3 < cl) ? __expf(v1.w - m) : 0.f;
#pragma unroll
  for (int off = 32; off > 0; off >>= 1) s += __shfl_down(s, off);
  if ((tid & 63) == 0) red[4 + (tid >> 6)] = s;
  __syncthreads();
  s = red[4] + red[5] + red[6] + red[7];

  if (tid == 0) {
    m_out[(size_t)b * JJ + j] = m;
    r_out[(size_t)b * JJ + j] = 1.f / s;
  }
}

// ---------------- Kernel C: out[b,t] = sum_{j<qlen} exp(S-m)*r ---------------
__global__ __launch_bounds__(256)
void out_kernel(const float* __restrict__ S, const float* __restrict__ m_arr,
                const float* __restrict__ r_arr, const int* __restrict__ qlen,
                const int* __restrict__ clen, float* __restrict__ out) {
  const int b = blockIdx.y;
  const int t = blockIdx.x * 256 + threadIdx.x;
  const int ql = qlen[b];
  const int cl = clen[b];

  __shared__ float lm[JJ];
  __shared__ float lr[JJ];
  if (threadIdx.x < ql) {
    lm[threadIdx.x] = m_arr[(size_t)b * JJ + threadIdx.x];
    lr[threadIdx.x] = r_arr[(size_t)b * JJ + threadIdx.x];
  }
  __syncthreads();

  float acc = 0.f;
  if (t < cl) {
    const float* col = S + (size_t)b * JJ * TT + t;
#pragma unroll 4
    for (int j = 0; j < ql; j++) {
      acc += __expf(col[(size_t)j * TT] - lm[j]) * lr[j];
    }
  }
  out[(size_t)b * TT + t] = acc;
}

extern "C" void kernel_launch(void* const* d_in, const int* in_sizes, int n_in,
                              void* d_out, int out_size, void* d_ws, size_t ws_size,
                              hipStream_t stream) {
  const float* question = (const float*)d_in[0];  // (B,J,D)
  const float* context  = (const float*)d_in[1];  // (B,T,D)
  const int*   qlen     = (const int*)d_in[2];    // (B,)
  const int*   clen     = (const int*)d_in[3];    // (B,)
  const float* weight   = (const float*)d_in[4];  // (D,1)
  float* out = (float*)d_out;                     // (B,T,1) f32

  // Workspace: S (B*J*T f32 = 64 MB) + m (B*J) + r (B*J)
  float* S = (float*)d_ws;
  float* m_arr = S + (size_t)BB * JJ * TT;
  float* r_arr = m_arr + (size_t)BB * JJ;

  sim_gemm_mfma<<<dim3(TT / 128, BB), 256, 0, stream>>>(question, context, weight, S);
  softmax_stats_kernel<<<dim3(JJ, BB), 256, 0, stream>>>(S, qlen, clen, m_arr, r_arr);
  out_kernel<<<dim3(TT / 256, BB), 256, 0, stream>>>(S, m_arr, r_arr, qlen, clen, out);
}